// Round 5
// baseline (626.083 us; speedup 1.0000x reference)
//
#include <hip/hip_runtime.h>
#include <hip/hip_bf16.h>
#include <math.h>
#include <stdint.h>

#define TT 2080
#define DM 512
#define DI 2048
#define NH 8
#define DH 64
#define NMTOK 16
#define NLAYER 4
#define QKV_N 1536
#define ATT_SCALE 0.125f
#define SPLIT 8
#define WT_STRIDE 3407872   // shorts per layer's transposed-weight block
#define QRP_HEAD 2200640    // shorts per head of packed QR triangle (rowbase(2080))

typedef short bf16x8 __attribute__((ext_vector_type(8)));
typedef float f32x4 __attribute__((ext_vector_type(4)));
typedef unsigned short ushort_t;

__device__ __forceinline__ ushort_t f2bf(float f) {
  __hip_bfloat16 h = __float2bfloat16(f);
  return *reinterpret_cast<ushort_t*>(&h);
}
__device__ __forceinline__ float bfbits2f(unsigned int hi_bits) {
  return __uint_as_float(hi_bits);
}
__device__ __forceinline__ float bf2f(ushort_t u) {
  return bfbits2f(((unsigned int)u) << 16);
}
__device__ __forceinline__ void unpack8(uint4 v, float* f) {
  f[0] = bfbits2f(v.x << 16); f[1] = bfbits2f(v.x & 0xffff0000u);
  f[2] = bfbits2f(v.y << 16); f[3] = bfbits2f(v.y & 0xffff0000u);
  f[4] = bfbits2f(v.z << 16); f[5] = bfbits2f(v.z & 0xffff0000u);
  f[6] = bfbits2f(v.w << 16); f[7] = bfbits2f(v.w & 0xffff0000u);
}
__device__ __forceinline__ unsigned int pack2(ushort_t lo, ushort_t hi) {
  return (unsigned int)lo | ((unsigned int)hi << 16);
}
// Barrier draining LDS ops only — leaves global (vmcnt) loads in flight.
__device__ __forceinline__ void barrier_lds() {
  asm volatile("s_waitcnt lgkmcnt(0)" ::: "memory");
  __builtin_amdgcn_s_barrier();
}
// Barrier draining everything (used to retire global_load_lds prefetches).
__device__ __forceinline__ void barrier_all() {
  asm volatile("s_waitcnt vmcnt(0) lgkmcnt(0)" ::: "memory");
  __builtin_amdgcn_s_barrier();
}
// global -> LDS direct copy, 16B per lane. LDS dest must be wave-uniform
// base + lane*16 (contract of global_load_lds); our chunk mapping satisfies it.
__device__ __forceinline__ void gload16(const ushort_t* g, ushort_t* l) {
  __builtin_amdgcn_global_load_lds(
      (__attribute__((address_space(1))) void*)(uintptr_t)g,
      (__attribute__((address_space(3))) void*)(uintptr_t)l, 16, 0, 0);
}
// Packed QR triangle: row i stores width W_i = ceil4(i+17):
//   p in [0, i]   -> BD value for col j = p           (causal part, p == j!)
//   p = i+1+w     -> wrap value qr[i].r[w], w in [0,16)
__device__ __forceinline__ size_t qr_rowbase(int i) {
  int m = i & 3;
  int r = (m == 0) ? 0 : (m == 1) ? 3 : (m == 2) ? 5 : 6;
  return (size_t)i * (i + 33) / 2 + 6 * (i >> 2) + r;
}
// ---- fragment-tiled (FT) layout --------------------------------------------
// Matrix X[R][K] (bf16) stored as 1024B blocks of (16 r x 32 k); block index
// (r>>4)*(K>>5) + (k>>5); within a block, lane = ((k>>3)&3)*16 + (r&15) holds
// 8 consecutive k-elements = EXACTLY the mfma_f32_16x16x32_bf16 A/B fragment
// order: ds_read_b128 at base+lane*16 is conflict-free, and global_load_lds
// staging is a straight linear copy.
__device__ __forceinline__ size_t ft512(int r, int c) {  // K = 512 (KT = 16)
  return (((size_t)(r >> 4) * 16 + (c >> 5)) << 9) + (((c >> 3) & 3) << 7) +
         ((r & 15) << 3) + (c & 7);
}

// ---- fused prep: all 4 layers' weight transposes + build w/pos ------------
__global__ __launch_bounds__(256) void k_prep(
    const float* __restrict__ Wqkv, const float* __restrict__ Wr,
    const float* __restrict__ Wo, const float* __restrict__ W1,
    const float* __restrict__ W2, ushort_t* __restrict__ dstAll,
    const float* __restrict__ we, const float* __restrict__ mem,
    float* __restrict__ w, ushort_t* __restrict__ wbft,
    ushort_t* __restrict__ posft) {
  const int tid = threadIdx.x;
  if (blockIdx.x >= 13312) {  // ---- build ----
    int idx = (blockIdx.x - 13312) * 256 + tid;
    if (idx >= TT * DM) return;
    int t = idx >> 9, d = idx & 511;
    float v;
    if (t < NMTOK) v = mem[t * DM + d];
    else if (t < NMTOK + 2048) v = we[(t - NMTOK) * DM + d];
    else v = mem[(t - (NMTOK + 2048)) * DM + d];
    w[idx] = v;
    wbft[ft512(t, d)] = f2bf(v);
    float p = (float)(TT - 1 - t);
    int i2 = d & 255;
    // 1/10000^(2*i2/512) = exp(-i2 * ln(1e4)/256); bf16 output absorbs error
    float freq = __expf(-0.035977892f * (float)i2);
    float ang = p * freq;
    posft[ft512(t, d)] = f2bf((d < 256) ? __sinf(ang) : __cosf(ang));
    return;
  }
  // ---- transpose+cast, layer l ----
  __shared__ float tl[32][33];
  const int l = blockIdx.x / 3328;
  int idx = blockIdx.x % 3328;
  const float* src;
  ushort_t* dst = dstAll + (size_t)l * WT_STRIDE;
  int K, N, local;
  bool isFT = true;
  if (idx < 768)       { src = Wqkv + (size_t)l * 512 * 1536; K = 512;  N = 1536; local = idx; }
  else if (idx < 1024) { src = Wr   + (size_t)l * 512 * 512;  dst += 786432;  K = 512;  N = 512;  local = idx - 768; }
  else if (idx < 1280) { src = Wo   + (size_t)l * 512 * 512;  dst += 1048576; K = 512;  N = 512;  local = idx - 1024; isFT = false; }
  else if (idx < 2304) { src = W1   + (size_t)l * 512 * 2048; dst += 1310720; K = 512;  N = 2048; local = idx - 1280; }
  else                 { src = W2   + (size_t)l * 2048 * 512; dst += 2359296; K = 2048; N = 512;  local = idx - 2304; }
  const int ntiles = N / 32;
  const int n0 = (local % ntiles) * 32, k0 = (local / ntiles) * 32;
#pragma unroll
  for (int p = 0; p < 4; ++p) {
    int row = (tid >> 5) + 8 * p, col = tid & 31;
    tl[row][col] = src[(size_t)(k0 + row) * N + n0 + col];  // tl[k][n]
  }
  __syncthreads();
  if (isFT) {
    if (tid < 128) {
      int b = tid >> 6, l2 = tid & 63;
      int nn = b * 16 + (l2 & 15);
      int kq = (l2 >> 4) * 8;
      ushort_t t8[8];
#pragma unroll
      for (int e = 0; e < 8; ++e) t8[e] = f2bf(tl[kq + e][nn]);
      size_t ad = (((size_t)((n0 >> 4) + b) * (K >> 5) + (k0 >> 5)) << 9) +
                  ((size_t)l2 << 3);
      *(uint4*)&dst[ad] = *(uint4*)t8;
    }
  } else {
#pragma unroll
    for (int p = 0; p < 4; ++p) {
      int n = (tid >> 5) + 8 * p, k = tid & 31;
      dst[(size_t)(n0 + n) * K + k0 + k] = f2bf(tl[k][n]);
    }
  }
}

// -------- bf16 MFMA GEMM body, 32x64 tile, register prefetch (Wo only) ----
__device__ __forceinline__ void gemm32x64_body(const ushort_t* __restrict__ A,
                                               const ushort_t* __restrict__ Bt,
                                               const float* __restrict__ bias,
                                               float* __restrict__ C,
                                               ushort_t* __restrict__ Cb,
                                               int N, int K, int flags,
                                               int m0, int n0) {
  __shared__ short As[32][72];
  __shared__ short Bs[64][72];
  const int tid = threadIdx.x;
  const int lane = tid & 63, wv = tid >> 6;
  const int wm = (wv >> 1) * 16, wn = (wv & 1) * 32;
  const int lm = lane & 15, quad = lane >> 4;
  const int sr = tid >> 3, sc8 = (tid & 7) * 8;

  f32x4 acc[2];
  acc[0] = (f32x4)(0.f); acc[1] = (f32x4)(0.f);

  auto loadA = [&](int k0) -> uint4 {
    return *(const uint4*)&A[(size_t)(m0 + sr) * K + k0 + sc8];
  };
  auto loadB = [&](int row, int k0) -> uint4 {
    return *(const uint4*)&Bt[(size_t)(n0 + row) * K + k0 + sc8];
  };

  uint4 aC = loadA(0), b0C = loadB(sr, 0), b1C = loadB(sr + 32, 0);

  for (int k0 = 0; k0 < K; k0 += 64) {
    const int kn = (k0 + 64 < K) ? k0 + 64 : k0;  // clamped tail reload
    uint4 aN = loadA(kn), b0N = loadB(sr, kn), b1N = loadB(sr + 32, kn);
    barrier_lds();  // prev ds_reads done; vm prefetches stay in flight
    *(uint4*)&As[sr][sc8] = aC;
    *(uint4*)&Bs[sr][sc8] = b0C;
    *(uint4*)&Bs[sr + 32][sc8] = b1C;
    barrier_lds();
#pragma unroll
    for (int kk = 0; kk < 64; kk += 32) {
      bf16x8 a = *(const bf16x8*)&As[wm + lm][kk + quad * 8];
      bf16x8 b0 = *(const bf16x8*)&Bs[wn + lm][kk + quad * 8];
      bf16x8 b1 = *(const bf16x8*)&Bs[wn + 16 + lm][kk + quad * 8];
      acc[0] = __builtin_amdgcn_mfma_f32_16x16x32_bf16(a, b0, acc[0], 0, 0, 0);
      acc[1] = __builtin_amdgcn_mfma_f32_16x16x32_bf16(a, b1, acc[1], 0, 0, 0);
    }
    aC = aN; b0C = b0N; b1C = b1N;
  }
#pragma unroll
  for (int nt = 0; nt < 2; ++nt) {
    int col = n0 + wn + nt * 16 + lm;
    float bv = (flags & 1) ? bias[col] : 0.f;
#pragma unroll
    for (int t = 0; t < 4; ++t) {
      int row = m0 + wm + quad * 4 + t;
      float v = acc[nt][t] + bv;
      if (flags & 2) v = fmaxf(v, 0.f);
      if (flags & 4) Cb[(size_t)row * N + col] = f2bf(v);
      else C[(size_t)row * N + col] = v;
    }
  }
}

__global__ __launch_bounds__(256) void k_gemm_mfma(const ushort_t* __restrict__ A,
                                                   const ushort_t* __restrict__ Bt,
                                                   const float* __restrict__ bias,
                                                   float* __restrict__ C,
                                                   ushort_t* __restrict__ Cb,
                                                   int N, int K, int flags) {
  gemm32x64_body(A, Bt, bias, C, Cb, N, K, flags, blockIdx.y * 32, blockIdx.x * 64);
}

// -------- FT GEMM: 64x128 tile, 4 waves x (32x64), global_load_lds staging,
// conflict-free fragment ds_reads, double-buffered (2 x 24KB LDS).
// flags: 1=+bias, 2=relu. omode: 0=fp32 rm, 1=bf16 rm, 2=FT(cftKT),
// 3=q(qwft=v+rwb FT, qrb=v+rrb rm), 4=k(kft FT, col-512), 5=v(vtft V^T FT).
__device__ __forceinline__ void gemm_ft_body(
    ushort_t* smem, const ushort_t* __restrict__ A, const ushort_t* __restrict__ Bt,
    const float* __restrict__ bias, int N, int K, int kBeg, int kEnd,
    int m0, int n0, int flags, int omode,
    float* __restrict__ Cf, ushort_t* __restrict__ Cb, int cftKT,
    ushort_t* __restrict__ aux, const float* __restrict__ rwb,
    const float* __restrict__ rrb) {
  const int tid = threadIdx.x;
  const int lane = tid & 63, wv = tid >> 6;
  const int wm = (wv >> 1) * 32, wn = (wv & 1) * 64;
  const int lm = lane & 15, quad = lane >> 4;
  const int AKT = K >> 5;                 // global k-tiles per 16-row block
  const int mt0 = m0 >> 4, nt0 = n0 >> 4;
  const int kt0 = kBeg >> 5;

  f32x4 acc[2][4];
#pragma unroll
  for (int i = 0; i < 2; ++i)
#pragma unroll
    for (int j = 0; j < 4; ++j) acc[i][j] = (f32x4)(0.f);

  auto stage = [&](ushort_t* dA, int ktg) {
    ushort_t* dB = dA + 4096;
#pragma unroll
    for (int it = 0; it < 6; ++it) {
      const int c = (it << 8) + tid;
      if (it < 2) {  // A chunks: c in [0,512)
        const int blk = c >> 6, ln = c & 63;
        gload16(A + (((size_t)(mt0 + (blk >> 1)) * AKT + ktg + (blk & 1)) << 9) + (ln << 3),
                dA + (c << 3));
      } else {       // B chunks: cB in [0,1024)
        const int cB = c - 512;
        const int blk = cB >> 6, ln = cB & 63;
        gload16(Bt + (((size_t)(nt0 + (blk >> 1)) * AKT + ktg + (blk & 1)) << 9) + (ln << 3),
                dB + (cB << 3));
      }
    }
  };
  auto compute = [&](const ushort_t* dA) {
    const ushort_t* dB = dA + 4096;
#pragma unroll
    for (int kk = 0; kk < 2; ++kk) {
      bf16x8 a[2], b[4];
#pragma unroll
      for (int i = 0; i < 2; ++i)
        a[i] = *(const bf16x8*)&dA[((((wm >> 4) + i) << 1) + kk) * 512 + (lane << 3)];
#pragma unroll
      for (int j = 0; j < 4; ++j)
        b[j] = *(const bf16x8*)&dB[((((wn >> 4) + j) << 1) + kk) * 512 + (lane << 3)];
#pragma unroll
      for (int i = 0; i < 2; ++i)
#pragma unroll
        for (int j = 0; j < 4; ++j)
          acc[i][j] = __builtin_amdgcn_mfma_f32_16x16x32_bf16(a[i], b[j], acc[i][j], 0, 0, 0);
    }
  };

  const int nIter = (kEnd - kBeg) >> 6;  // always even (8) here
  stage(smem, kt0);
  __syncthreads();
  for (int t = 0; t < nIter; t += 2) {
    if (t + 1 < nIter) stage(smem + 12288, kt0 + (t + 1) * 2);
    compute(smem);
    __syncthreads();
    if (t + 2 < nIter) stage(smem, kt0 + (t + 2) * 2);
    compute(smem + 12288);
    __syncthreads();
  }

#pragma unroll
  for (int i = 0; i < 2; ++i) {
    const int rowb = m0 + wm + i * 16 + quad * 4;
#pragma unroll
    for (int j = 0; j < 4; ++j) {
      const int col = n0 + wn + j * 16 + lm;
      const float bv = (flags & 1) ? bias[col] : 0.f;
#pragma unroll
      for (int t2 = 0; t2 < 4; ++t2) {
        const int row = rowb + t2;
        float v = acc[i][j][t2] + bv;
        if (flags & 2) v = fmaxf(v, 0.f);
        if (omode == 0) {
          Cf[(size_t)row * N + col] = v;
        } else if (omode == 1) {
          Cb[(size_t)row * N + col] = f2bf(v);
        } else if (omode == 2) {
          Cb[(((size_t)(row >> 4) * cftKT + (col >> 5)) << 9) +
             (((col >> 3) & 3) << 7) + ((row & 15) << 3) + (col & 7)] = f2bf(v);
        } else if (omode == 3) {
          Cb[ft512(row, col)] = f2bf(v + rwb[col]);
          aux[(size_t)row * DM + col] = f2bf(v + rrb[col]);
        } else if (omode == 4) {
          Cb[ft512(row, col - 512)] = f2bf(v);
        } else {  // omode 5: V^T FT, r = v-dim, c = token
          const int dv = col - 1024;
          Cb[((size_t)(dv >> 4) * 65 + (row >> 5)) * 512 +
             (((row >> 3) & 3) << 7) + ((dv & 15) << 3) + (row & 7)] = f2bf(v);
        }
      }
    }
  }
}

// merged QKV + Wr GEMMs (FT); q-part -> qwft(+rwb) & qrb(+rrb); k -> kft;
// v -> vtft (V^T FT); Wr -> rbg (rm)
__global__ __launch_bounds__(256) void k_gemm_qkvwr_ft(
    const ushort_t* __restrict__ wbft, const ushort_t* __restrict__ posft,
    const ushort_t* __restrict__ qkvT, const ushort_t* __restrict__ wrT,
    ushort_t* __restrict__ qwft, ushort_t* __restrict__ kft,
    ushort_t* __restrict__ vtft, ushort_t* __restrict__ rbg,
    ushort_t* __restrict__ qrb, const float* __restrict__ rwb,
    const float* __restrict__ rrb) {
  __shared__ ushort_t smem[24576];
  int m0 = blockIdx.y * 64;
  if (m0 + 64 > TT) m0 = TT - 64;  // overlapped last tile (dup writes benign)
  const int bx = blockIdx.x;
  if (bx < 12) {
    const int om = (bx < 4) ? 3 : (bx < 8 ? 4 : 5);
    ushort_t* dst = (om == 3) ? qwft : (om == 4) ? kft : vtft;
    gemm_ft_body(smem, wbft, qkvT, nullptr, QKV_N, DM, 0, DM, m0, bx * 128,
                 0, om, nullptr, dst, 0, qrb, rwb, rrb);
  } else {
    gemm_ft_body(smem, posft, wrT, nullptr, DM, DM, 0, DM, m0, (bx - 12) * 128,
                 0, 1, nullptr, rbg, 0, nullptr, nullptr, nullptr);
  }
}

// FFN1: wbft x w1T -> ff1ft (FT, K_out = DI), bias+relu
__global__ __launch_bounds__(256) void k_ffn1_ft(const ushort_t* __restrict__ wbft,
                                                 const ushort_t* __restrict__ w1T,
                                                 const float* __restrict__ b1l,
                                                 ushort_t* __restrict__ ff1ft) {
  __shared__ ushort_t smem[24576];
  int m0 = blockIdx.y * 64;
  if (m0 + 64 > TT) m0 = TT - 64;
  gemm_ft_body(smem, wbft, w1T, b1l, DI, DM, 0, DM, m0, blockIdx.x * 128,
               1 | 2, 2, nullptr, ff1ft, DI >> 5, nullptr, nullptr, nullptr);
}

// FFN2: ff1ft x w2T -> fp32 partials (split-K=4); bias folded into split 0
__global__ __launch_bounds__(256) void k_ffn2_ft(const ushort_t* __restrict__ ff1ft,
                                                 const ushort_t* __restrict__ w2T,
                                                 const float* __restrict__ b2l,
                                                 float* __restrict__ ff2p) {
  __shared__ ushort_t smem[24576];
  int m0 = blockIdx.y * 64;
  if (m0 + 64 > TT) m0 = TT - 64;
  const int s = blockIdx.z;
  gemm_ft_body(smem, ff1ft, w2T, b2l, DM, DI, s * 512, s * 512 + 512, m0,
               blockIdx.x * 128, (s == 0) ? 1 : 0, 0,
               ff2p + (size_t)s * TT * DM, nullptr, 0, nullptr, nullptr, nullptr);
}

// ---- QR GEMM: QR[h][i][k] = qr_i . r_k, written as packed causal triangle -
__global__ __launch_bounds__(256) void k_qr(const ushort_t* __restrict__ qrb,
                                            const ushort_t* __restrict__ rbg,
                                            ushort_t* __restrict__ qrp) {
  const int h = blockIdx.z;
  const int m0 = blockIdx.y * 32, n0 = blockIdx.x * 64;
  if (!(n0 == 0 || n0 + 63 >= TT - 32 - m0)) return;
  __shared__ short As[32][72];
  __shared__ short Bs[64][72];
  const int tid = threadIdx.x;
  const int lane = tid & 63, wv = tid >> 6;
  const int wm = (wv >> 1) * 16, wn = (wv & 1) * 32;
  const int lm = lane & 15, quad = lane >> 4;
  const int sr = tid >> 3, sc8 = (tid & 7) * 8;
  const uint4 zero4 = make_uint4(0, 0, 0, 0);

  *(uint4*)&As[sr][sc8] = *(const uint4*)&qrb[(size_t)(m0 + sr) * DM + h * DH + sc8];
  int br0 = n0 + sr, br1 = n0 + sr + 32;
  *(uint4*)&Bs[sr][sc8] =
      (br0 < TT) ? *(const uint4*)&rbg[(size_t)br0 * DM + h * DH + sc8] : zero4;
  *(uint4*)&Bs[sr + 32][sc8] =
      (br1 < TT) ? *(const uint4*)&rbg[(size_t)br1 * DM + h * DH + sc8] : zero4;
  __syncthreads();

  f32x4 acc[2];
  acc[0] = (f32x4)(0.f); acc[1] = (f32x4)(0.f);
#pragma unroll
  for (int kk = 0; kk < 64; kk += 32) {
    bf16x8 a = *(const bf16x8*)&As[wm + lm][kk + quad * 8];
    bf16x8 b0 = *(const bf16x8*)&Bs[wn + lm][kk + quad * 8];
    bf16x8 b1 = *(const bf16x8*)&Bs[wn + 16 + lm][kk + quad * 8];
    acc[0] = __builtin_amdgcn_mfma_f32_16x16x32_bf16(a, b0, acc[0], 0, 0, 0);
    acc[1] = __builtin_amdgcn_mfma_f32_16x16x32_bf16(a, b1, acc[1], 0, 0, 0);
  }
  const size_t hb = (size_t)h * QRP_HEAD;
#pragma unroll
  for (int nt = 0; nt < 2; ++nt) {
    int col = n0 + wn + nt * 16 + lm;
    if (col >= TT) continue;
#pragma unroll
    for (int t = 0; t < 4; ++t) {
      int row = m0 + wm + quad * 4 + t;
      float v = acc[nt][t];
      int p = row + col - (TT - 1);  // packed causal index (== j)
      size_t rb = hb + qr_rowbase(row);
      if (p >= 0) qrp[rb + p] = f2bf(v);
      if (col < 16) qrp[rb + row + 1 + col] = f2bf(v);  // wrap slot
    }
  }
}

// ------- MFMA flash attention, KVBLK=64, split-j, FT-staged Q/K/V^T -------
// Half the iterations/barriers of the 32-wide version; phase C has a
// branch-free fast path for all-causal tiles (every tile except the diagonal).
__global__ __launch_bounds__(256) void k_attn(const ushort_t* __restrict__ qwft,
                                              const ushort_t* __restrict__ kft,
                                              const ushort_t* __restrict__ vtft,
                                              const ushort_t* __restrict__ qrp,
                                              float* __restrict__ mlP,
                                              ushort_t* __restrict__ opP) {
  const int h = blockIdx.y;
  const int qt = 64 - blockIdx.x;  // heavy q-tiles dispatch first
  const int qd = qt >> 1;          // diagonal 64-wide j-tile index
  const int c = blockIdx.z;
  if (c > qd) return;              // empty chunk
  const int i0 = qt * 32;
  const int tid = threadIdx.x;
  const int lane = tid & 63, wv = tid >> 6;
  const int lm = lane & 15, quad = lane >> 4;

  __shared__ ushort_t qwl[2048];     // (q+rwb) 32x64: blocks [rb2][kt2]
  __shared__ ushort_t kl[2][4096];   // K 64x64 dbuf: blocks [jr4][kt2]
  __shared__ ushort_t vtl[2][4096];  // V^T 64x64 dbuf: blocks [dt4][jb2]
  __shared__ ushort_t pbl[2048];     // P 32x64: blocks [it2][kt2]
  __shared__ float st[32][67];       // scores fp32 (odd stride: ~2-way max)
  __shared__ float m_s[32], l_s[32], alpha_s[32];

  const int ii = tid >> 3, g = tid & 7, jjb = g * 8;
  const int i = i0 + ii;
  const size_t hb = (size_t)h * QRP_HEAD;
  const size_t qrRow = hb + qr_rowbase(i);               // this thread's QR row
  const size_t qrRowW = hb + qr_rowbase(i + 1) + i + 2;  // wrap base (i+1 row)

  auto stageKV = [&](int j0, int buf) {
    const int jb0 = j0 >> 5;
    const int jb1 = (jb0 + 1 > 64) ? 64 : jb0 + 1;  // clamp: dup valid V rows
#pragma unroll
    for (int it = 0; it < 2; ++it) {
      const int cc = (it << 8) + tid;
      const int blk = cc >> 6, ln = cc & 63;
      int jr = (j0 >> 4) + (blk >> 1);
      if (jr > 129) jr = 129;  // clamp: dup valid K rows (masked anyway)
      gload16(kft + ((size_t)jr * 16 + h * 2 + (blk & 1)) * 512 + (ln << 3),
              kl[buf] + (cc << 3));
      const int jb = (blk & 1) ? jb1 : jb0;
      gload16(vtft + ((size_t)(h * 4 + (blk >> 1)) * 65 + jb) * 512 + (ln << 3),
              vtl[buf] + (cc << 3));
    }
  };

  {  // prologue: Q tile (4 blocks) + first K/V tile, all direct-to-LDS
    const int blk = tid >> 6, ln = tid & 63;
    gload16(qwft + (((size_t)((i0 >> 4) + (blk >> 1)) * 16) + h * 2 + (blk & 1)) * 512 +
                (ln << 3),
            qwl + (tid << 3));
    stageKV(c * 64, 0);
  }
  if (tid < 32) { m_s[tid] = -INFINITY; l_s[tid] = 0.f; }
  barrier_all();

  // Q fragments are loop-invariant: hoist to registers
  const int rb = wv >> 1;
  bf16x8 aQ[2];
#pragma unroll
  for (int kt = 0; kt < 2; ++kt)
    aQ[kt] = *(const bf16x8*)&qwl[(rb * 2 + kt) * 512 + (lane << 3)];

  f32x4 oA = (f32x4)(0.f);  // O^T accum, d-tile=wv, i = i0+lm
  f32x4 oB = (f32x4)(0.f);  // i = i0+16+lm

  int cur = 0;
  for (int jd = c; jd <= qd; jd += SPLIT) {
    const int j0 = jd * 64;
    if (jd + SPLIT <= qd) stageKV((jd + SPLIT) * 64, cur ^ 1);

    {  // ---- phase B: 32x64 AC scores -> st ----
#pragma unroll
      for (int s2 = 0; s2 < 2; ++s2) {
        const int cb = (wv & 1) * 2 + s2;
        f32x4 ac = (f32x4)(0.f);
#pragma unroll
        for (int kt = 0; kt < 2; ++kt) {
          bf16x8 b = *(const bf16x8*)&kl[cur][(cb * 2 + kt) * 512 + (lane << 3)];
          ac = __builtin_amdgcn_mfma_f32_16x16x32_bf16(aQ[kt], b, ac, 0, 0, 0);
        }
#pragma unroll
        for (int t = 0; t < 4; ++t)
          st[rb * 16 + quad * 4 + t][cb * 16 + lm] = ac[t];
      }
    }
    barrier_lds();

    {  // ---- phase C: score assembly + online softmax (8 cols/thread) ----
      float sreg[8];
      if (jd < qd) {  // fast path: every element causal (j <= i guaranteed)
        uint2 q0 = *(const uint2*)&qrp[qrRow + j0 + jjb];
        uint2 q1 = *(const uint2*)&qrp[qrRow + j0 + jjb + 4];
        float bd[8];
        bd[0] = bf2f((ushort_t)(q0.x & 0xffffu)); bd[1] = bf2f((ushort_t)(q0.x >> 16));
        bd[2] = bf2f((ushort_t)(q0.y & 0xffffu)); bd[3] = bf2f((ushort_t)(q0.y >> 16));
        bd[4] = bf2f((ushort_t)(q1.x & 0xffffu)); bd[5] = bf2f((ushort_t)(q1.x >> 16));
        bd[6] = bf2f((ushort_t)(q1.y & 0xffffu)); bd[7] = bf2f((ushort_t)(q1.y >> 16));
#pragma unroll
        for (int u = 0; u < 8; ++u)
          sreg[u] = (st[ii][jjb + u] + bd[u]) * ATT_SCALE;
      } else {  // diagonal tile: mask + mem-corner + wrap handling
        const size_t LIM = (size_t)NH * QRP_HEAD - 4;  // clamp global tail reads
        size_t aA = qrRow + j0 + jjb, aB = aA + 4;
        if (aA > LIM) aA = LIM;
        if (aB > LIM) aB = LIM;
        uint2 q0 = *(const uint2*)&qrp[aA];
        uint2 q1 = *(const uint2*)&qrp[aB];
        float bd[8];
        bd[0] = bf2f((ushort_t)(q0.x & 0xffffu)); bd[1] = bf2f((ushort_t)(q0.x >> 16));
        bd[2] = bf2f((ushort_t)(q0.y & 0xffffu)); bd[3] = bf2f((ushort_t)(q0.y >> 16));
        bd[4] = bf2f((ushort_t)(q1.x & 0xffffu)); bd[5] = bf2f((ushort_t)(q1.x >> 16));
        bd[6] = bf2f((ushort_t)(q1.y & 0xffffu)); bd[7] = bf2f((ushort_t)(q1.y >> 16));
#pragma unroll
        for (int u = 0; u < 8; ++u) {
          const int j = j0 + jjb + u;
          const float acv = st[ii][jjb + u];
          float s;
          if (j <= i) {
            s = (acv + bd[u]) * ATT_SCALE;
          } else {
            bool inmem = (i < NMTOK && j < NMTOK) ||
                         (i >= TT - NMTOK && j >= TT - NMTOK && j < TT);
            if (!inmem) s = -1e30f;
            else if (j == i + 1) s = acv * ATT_SCALE;  // rel_shift zero-pad
            else s = (acv + bf2f(qrp[qrRowW + (j - i - 2)])) * ATT_SCALE;  // wrap
          }
          sreg[u] = s;
        }
      }
      float tmax = sreg[0];
#pragma unroll
      for (int u = 1; u < 8; ++u) tmax = fmaxf(tmax, sreg[u]);
#pragma unroll
      for (int off = 1; off < 8; off <<= 1) tmax = fmaxf(tmax, __shfl_xor(tmax, off));
      const float mold = m_s[ii];
      const float mnew = fmaxf(mold, tmax);
      const float alpha = __expf(mold - mnew);
      float p[8], psum = 0.f;
#pragma unroll
      for (int u = 0; u < 8; ++u) { p[u] = __expf(sreg[u] - mnew); psum += p[u]; }
#pragma unroll
      for (int off = 1; off < 8; off <<= 1) psum += __shfl_xor(psum, off);
      uint4 pk;
      pk.x = pack2(f2bf(p[0]), f2bf(p[1]));
      pk.y = pack2(f2bf(p[2]), f2bf(p[3]));
      pk.z = pack2(f2bf(p[4]), f2bf(p[5]));
      pk.w = pack2(f2bf(p[6]), f2bf(p[7]));
      // P in fragment order: block (it = ii>>4)*2 + (kt = g>>2)
      *(uint4*)&pbl[(((ii >> 4) * 2 + (g >> 2)) << 9) +
                    (((g & 3) * 16 + (ii & 15)) << 3)] = pk;
      if (g == 0) {
        m_s[ii] = mnew;
        l_s[ii] = l_s[ii] * alpha + psum;
        alpha_s[ii] = alpha;
      }
    }
    barrier_lds();

    {  // ---- phase D: O^T = O^T*alpha + V^T P^T (K=64 over 2 k-slots) ----
      float a0 = alpha_s[lm], a1 = alpha_s[16 + lm];
#pragma unroll
      for (int t = 0; t < 4; ++t) { oA[t] *= a0; oB[t] *= a1; }
#pragma unroll
      for (int kt = 0; kt < 2; ++kt) {
        bf16x8 av = *(const bf16x8*)&vtl[cur][(wv * 2 + kt) * 512 + (lane << 3)];
        bf16x8 p0 = *(const bf16x8*)&pbl[(kt << 9) + (lane << 3)];
        bf16x8 p1 = *(const bf16x8*)&pbl[((2 + kt) << 9) + (lane << 3)];
        oA = __builtin_amdgcn_mfma_f32_16x16x32_bf16(av, p0, oA, 0, 0, 0);
        oB = __builtin_amdgcn_mfma_f32_16x16x32_bf16(av, p1, oB, 0, 0, 0);
      }
    }
    barrier_all();  // retire prefetch + recycle buffers
    cur ^= 1;
  }

  {  // write partials: m, l (fp32) and un-normalized O (bf16, [i][d] layout)
    const int pidx = (qt * NH + h) * SPLIT + c;
    if (tid < 32) {
      mlP[(size_t)pidx * 64 + tid] = m_s[tid];
      mlP[(size_t)pidx * 64 + 32 + tid] = l_s[tid];
    }
    ushort_t o0[4], o1[4];
#pragma unroll
    for (int t = 0; t < 4; ++t) { o0[t] = f2bf(oA[t]); o1[t] = f2bf(oB[t]); }
    size_t ob = (size_t)pidx * 2048;
    *(uint2*)&opP[ob + (size_t)lm * 64 + wv * 16 + quad * 4] = *(uint2*)o0;
    *(uint2*)&opP[ob + (size_t)(16 + lm) * 64 + wv * 16 + quad * 4] = *(uint2*)o1;
  }
}

// -------- combine <=SPLIT chunk partials -> normalized attn output --------
__global__ __launch_bounds__(256) void k_attn_combine(const float* __restrict__ mlP,
                                                      const ushort_t* __restrict__ opP,
                                                      ushort_t* __restrict__ attnb) {
  const int qt = blockIdx.x, h = blockIdx.y;
  const int qd = qt >> 1;
  const int nc = (qd + 1 < SPLIT) ? qd + 1 : SPLIT;  // KVBLK=64 chunk count
  const int tid = threadIdx.x;
  const int i = tid >> 3, d8 = (tid & 7) * 8;
  const size_t base = (size_t)(qt * NH + h) * SPLIT;
  float m[SPLIT], l[SPLIT], wgt[SPLIT];
  float M = -INFINITY;
  for (int cc = 0; cc < nc; ++cc) {
    m[cc] = mlP[(base + cc) * 64 + i];
    l[cc] = mlP[(base + cc) * 64 + 32 + i];
    M = fmaxf(M, m[cc]);
  }
  float L = 0.f;
  for (int cc = 0; cc < nc; ++cc) { wgt[cc] = __expf(m[cc] - M); L += l[cc] * wgt[cc]; }
  float acc[8] = {0, 0, 0, 0, 0, 0, 0, 0};
  for (int cc = 0; cc < nc; ++cc) {
    uint4 v = *(const uint4*)&opP[(base + cc) * 2048 + (size_t)i * 64 + d8];
    float f[8]; unpack8(v, f);
#pragma unroll
    for (int k = 0; k < 8; ++k) acc[k] += wgt[cc] * f[k];
  }
  const float inv = 1.f / L;
  ushort_t o8[8];
#pragma unroll
  for (int k = 0; k < 8; ++k) o8[k] = f2bf(acc[k] * inv);
  *(uint4*)&attnb[(size_t)(qt * 32 + i) * DM + h * DH + d8] = *(uint4*)o8;
}

// -------- w' = LayerNorm(w + sum(delta parts)) * g + b ---------------------
__global__ __launch_bounds__(256) void k_addln(const float* __restrict__ w,
                                               float* __restrict__ wout,
                                               ushort_t* __restrict__ wbft,
                                               const float* __restrict__ delta,
                                               int nparts,
                                               const float* __restrict__ gamma,
                                               const float* __restrict__ beta) {
  const int row = blockIdx.x;
  const int tid = threadIdx.x;
  __shared__ float red[4], red2[4];
  __shared__ float sm[512];
  size_t base = (size_t)row * DM;
  float x0 = w[base + tid];
  float x1 = w[base + tid + 256];
  for (int p = 0; p < nparts; ++p) {
    x0 += delta[(size_t)p * TT * DM + base + tid];
    x1 += delta[(size_t)p * TT * DM + base + tid + 256];
  }
  float s = x0 + x1;
#pragma unroll
  for (int off = 1; off < 64; off <<= 1) s += __shfl_xor(s, off);
  if ((tid & 63) == 0) red[tid >> 6] = s;
  __syncthreads();
  float mu = (red[0] + red[1] + red[2] + red[3]) * (1.f / 512.f);
  float d0 = x0 - mu, d1 = x1 - mu;
  float v = d0 * d0 + d1 * d1;
#pragma unroll
  for (int off = 1; off < 64; off <<= 1) v += __shfl_xor(v, off);
  if ((tid & 63) == 0) red2[tid >> 6] = v;
  __syncthreads();
  float var = (red2[0] + red2[1] + red2[2] + red2[3]) * (1.f / 512.f);
  float rstd = rsqrtf(var + 1e-5f);
  float o0 = d0 * rstd * gamma[tid] + beta[tid];
  float o1 = d1 * rstd * gamma[tid + 256] + beta[tid + 256];
  wout[base + tid] = o0;
  wout[base + tid + 256] = o1;
  sm[tid] = o0; sm[tid + 256] = o1;
  __syncthreads();
  if (tid < 64) {
    const int d8 = tid << 3;
    ushort_t t8[8];
#pragma unroll
    for (int e = 0; e < 8; ++e) t8[e] = f2bf(sm[d8 + e]);
    *(uint4*)&wbft[ft512(row, d8)] = *(uint4*)t8;
  }
}

extern "C" void kernel_launch(void* const* d_in, const int* in_sizes, int n_in,
                              void* d_out, int out_size, void* d_ws, size_t ws_size,
                              hipStream_t stream) {
  const float* we   = (const float*)d_in[0];
  const float* mem  = (const float*)d_in[1];
  const float* Wqkv = (const float*)d_in[2];
  const float* Wr   = (const float*)d_in[3];
  const float* Wo   = (const float*)d_in[4];
  const float* ln1s = (const float*)d_in[5];
  const float* ln1b = (const float*)d_in[6];
  const float* W1   = (const float*)d_in[7];
  const float* b1   = (const float*)d_in[8];
  const float* W2   = (const float*)d_in[9];
  const float* b2   = (const float*)d_in[10];
  const float* ln2s = (const float*)d_in[11];
  const float* ln2b = (const float*)d_in[12];
  const float* rwb  = (const float*)d_in[13];
  const float* rrb  = (const float*)d_in[14];

  // ---- workspace layout (same footprint as before) ----
  float* w     = (float*)d_ws;                        // TT*DM fp32
  float* proj  = w + (size_t)TT * DM;                 // TT*DM fp32 (Wo out)
  ushort_t* wbft  = (ushort_t*)(proj + (size_t)TT * DM);  // TT*DM bf16 (FT)
  ushort_t* posft = wbft + (size_t)TT * DM;           // TT*DM bf16 (FT)
  ushort_t* attnb = posft + (size_t)TT * DM;          // TT*DM bf16 (rm)
  ushort_t* qkvB  = attnb + (size_t)TT * DM;          // TT*1536 bf16 region
  ushort_t* qwft  = qkvB;                             // TT*DM (Q+rwb, FT)
  ushort_t* kft   = qkvB + (size_t)TT * DM;           // TT*DM (K, FT)
  ushort_t* vtft  = qkvB + (size_t)2 * TT * DM;       // DM*TT (V^T, FT)
  ushort_t* rbg   = qkvB + (size_t)TT * QKV_N;        // TT*DM bf16 (rm)
  ushort_t* WtAll = rbg + (size_t)TT * DM;            // 4 layers x WT_STRIDE shorts
  ushort_t* opP   = WtAll + (size_t)NLAYER * WT_STRIDE;  // 65*8*SPLIT*2048 shorts
  float* mlP   = (float*)(opP + (size_t)65 * 8 * SPLIT * 2048);  // 65*8*SPLIT*64 f32
  ushort_t* qrb  = (ushort_t*)(mlP + (size_t)65 * 8 * SPLIT * 64);  // TT*DM bf16
  ushort_t* qrp  = qrb + (size_t)TT * DM;             // NH * QRP_HEAD shorts
  // overlays (time-shared, stream-ordered):
  ushort_t* ff1ft = qkvB;            // FT TT*DI bf16 spans qkv region + rbg
  float* ff2p  = (float*)opP;        // 4 split-K partials, 4*TT*DM f32 == |opP|
  const size_t OFF_QKVT = 0, OFF_WRT = 786432, OFF_WOT = 1048576,
               OFF_W1T = 1310720, OFF_W2T = 2359296;

  // all-layer weight transpose(+FT pack) + build in one dispatch
  k_prep<<<13312 + 4160, 256, 0, stream>>>(Wqkv, Wr, Wo, W1, W2, WtAll,
                                           we, mem, w, wbft, posft);

  dim3 gQW(16, 33);          // merged QKV (12 n-tiles) + Wr (4 n-tiles), 64x128
  dim3 gW1(16, 33);          // FFN1 64x128
  dim3 gW2(4, 33, 4);        // FFN2 64x128, split-K=4
  dim3 gDM32(DM / 64, 65);   // Wo (old 32x64 kernel)
  dim3 gQR(33, 65, NH);
  dim3 gA(65, NH, SPLIT);
  dim3 gC(65, NH);

  for (int l = 0; l < NLAYER; ++l) {
    const ushort_t* Wt = WtAll + (size_t)l * WT_STRIDE;
    k_gemm_qkvwr_ft<<<gQW, 256, 0, stream>>>(wbft, posft, Wt + OFF_QKVT,
                                             Wt + OFF_WRT, qwft, kft, vtft,
                                             rbg, qrb, rwb, rrb);
    k_qr<<<gQR, 256, 0, stream>>>(qrb, rbg, qrp);
    k_attn<<<gA, 256, 0, stream>>>(qwft, kft, vtft, qrp, mlP, opP);
    k_attn_combine<<<gC, 256, 0, stream>>>(mlP, opP, attnb);
    k_gemm_mfma<<<gDM32, 256, 0, stream>>>(attnb, Wt + OFF_WOT, nullptr, proj, nullptr,
                                           DM, DM, 0);
    k_addln<<<TT, 256, 0, stream>>>(w, w, wbft, proj, 1,
                                    ln1s + (size_t)l * DM, ln1b + (size_t)l * DM);
    k_ffn1_ft<<<gW1, 256, 0, stream>>>(wbft, Wt + OFF_W1T, b1 + (size_t)l * DI, ff1ft);
    k_ffn2_ft<<<gW2, 256, 0, stream>>>(ff1ft, Wt + OFF_W2T, b2 + (size_t)l * DM, ff2p);
    float* wout = (l == NLAYER - 1) ? (float*)d_out : w;
    k_addln<<<TT, 256, 0, stream>>>(w, wout, wbft, ff2p, 4,
                                    ln2s + (size_t)l * DM, ln2b + (size_t)l * DM);
  }
}

// Round 6
// 610.742 us; speedup vs baseline: 1.0251x; 1.0251x over previous
//
#include <hip/hip_runtime.h>
#include <hip/hip_bf16.h>
#include <math.h>
#include <stdint.h>

#define TT 2080
#define DM 512
#define DI 2048
#define NH 8
#define DH 64
#define NMTOK 16
#define NLAYER 4
#define QKV_N 1536
#define ATT_SCALE 0.125f
#define SPLIT 8
#define WT_STRIDE 3407872   // shorts per layer's transposed-weight block
#define QRP_HEAD 2200640    // shorts per head of packed QR triangle (rowbase(2080))

typedef short bf16x8 __attribute__((ext_vector_type(8)));
typedef float f32x4 __attribute__((ext_vector_type(4)));
typedef unsigned short ushort_t;

__device__ __forceinline__ ushort_t f2bf(float f) {
  __hip_bfloat16 h = __float2bfloat16(f);
  return *reinterpret_cast<ushort_t*>(&h);
}
__device__ __forceinline__ float bfbits2f(unsigned int hi_bits) {
  return __uint_as_float(hi_bits);
}
__device__ __forceinline__ float bf2f(ushort_t u) {
  return bfbits2f(((unsigned int)u) << 16);
}
__device__ __forceinline__ void unpack8(uint4 v, float* f) {
  f[0] = bfbits2f(v.x << 16); f[1] = bfbits2f(v.x & 0xffff0000u);
  f[2] = bfbits2f(v.y << 16); f[3] = bfbits2f(v.y & 0xffff0000u);
  f[4] = bfbits2f(v.z << 16); f[5] = bfbits2f(v.z & 0xffff0000u);
  f[6] = bfbits2f(v.w << 16); f[7] = bfbits2f(v.w & 0xffff0000u);
}
__device__ __forceinline__ unsigned int pack2(ushort_t lo, ushort_t hi) {
  return (unsigned int)lo | ((unsigned int)hi << 16);
}
// Barrier draining LDS ops only — leaves global (vmcnt) loads in flight.
__device__ __forceinline__ void barrier_lds() {
  asm volatile("s_waitcnt lgkmcnt(0)" ::: "memory");
  __builtin_amdgcn_s_barrier();
}
// Barrier draining everything (used to retire global_load_lds prefetches).
__device__ __forceinline__ void barrier_all() {
  asm volatile("s_waitcnt vmcnt(0) lgkmcnt(0)" ::: "memory");
  __builtin_amdgcn_s_barrier();
}
// global -> LDS direct copy, 16B per lane. LDS dest must be wave-uniform
// base + lane*16 (contract of global_load_lds); our chunk mapping satisfies it.
__device__ __forceinline__ void gload16(const ushort_t* g, ushort_t* l) {
  __builtin_amdgcn_global_load_lds(
      (__attribute__((address_space(1))) void*)(uintptr_t)g,
      (__attribute__((address_space(3))) void*)(uintptr_t)l, 16, 0, 0);
}
// Packed QR triangle: row i stores width W_i = ceil4(i+17):
//   p in [0, i]   -> BD value for col j = p           (causal part, p == j!)
//   p = i+1+w     -> wrap value qr[i].r[w], w in [0,16)
__device__ __forceinline__ size_t qr_rowbase(int i) {
  int m = i & 3;
  int r = (m == 0) ? 0 : (m == 1) ? 3 : (m == 2) ? 5 : 6;
  return (size_t)i * (i + 33) / 2 + 6 * (i >> 2) + r;
}
// ---- fragment-tiled (FT) layout --------------------------------------------
// Matrix X[R][K] (bf16) stored as 1024B blocks of (16 r x 32 k); block index
// (r>>4)*(K>>5) + (k>>5); within a block, lane = ((k>>3)&3)*16 + (r&15) holds
// 8 consecutive k-elements = EXACTLY the mfma_f32_16x16x32_bf16 A/B fragment
// order: ds_read_b128 at base+lane*16 is conflict-free, and global_load_lds
// staging is a straight linear copy.
__device__ __forceinline__ size_t ft512(int r, int c) {  // K = 512 (KT = 16)
  return (((size_t)(r >> 4) * 16 + (c >> 5)) << 9) + (((c >> 3) & 3) << 7) +
         ((r & 15) << 3) + (c & 7);
}

// ---- fused prep: all 4 layers' weight transposes + build w/pos ------------
__global__ __launch_bounds__(256) void k_prep(
    const float* __restrict__ Wqkv, const float* __restrict__ Wr,
    const float* __restrict__ Wo, const float* __restrict__ W1,
    const float* __restrict__ W2, ushort_t* __restrict__ dstAll,
    const float* __restrict__ we, const float* __restrict__ mem,
    float* __restrict__ w, ushort_t* __restrict__ wbft,
    ushort_t* __restrict__ posft) {
  const int tid = threadIdx.x;
  if (blockIdx.x >= 13312) {  // ---- build ----
    int idx = (blockIdx.x - 13312) * 256 + tid;
    if (idx >= TT * DM) return;
    int t = idx >> 9, d = idx & 511;
    float v;
    if (t < NMTOK) v = mem[t * DM + d];
    else if (t < NMTOK + 2048) v = we[(t - NMTOK) * DM + d];
    else v = mem[(t - (NMTOK + 2048)) * DM + d];
    w[idx] = v;
    wbft[ft512(t, d)] = f2bf(v);
    float p = (float)(TT - 1 - t);
    int i2 = d & 255;
    // 1/10000^(2*i2/512) = exp(-i2 * ln(1e4)/256); bf16 output absorbs error
    float freq = __expf(-0.035977892f * (float)i2);
    float ang = p * freq;
    posft[ft512(t, d)] = f2bf((d < 256) ? __sinf(ang) : __cosf(ang));
    return;
  }
  // ---- transpose+cast, layer l ----
  __shared__ float tl[32][33];
  const int l = blockIdx.x / 3328;
  int idx = blockIdx.x % 3328;
  const float* src;
  ushort_t* dst = dstAll + (size_t)l * WT_STRIDE;
  int K, N, local;
  bool isFT = true;
  if (idx < 768)       { src = Wqkv + (size_t)l * 512 * 1536; K = 512;  N = 1536; local = idx; }
  else if (idx < 1024) { src = Wr   + (size_t)l * 512 * 512;  dst += 786432;  K = 512;  N = 512;  local = idx - 768; }
  else if (idx < 1280) { src = Wo   + (size_t)l * 512 * 512;  dst += 1048576; K = 512;  N = 512;  local = idx - 1024; isFT = false; }
  else if (idx < 2304) { src = W1   + (size_t)l * 512 * 2048; dst += 1310720; K = 512;  N = 2048; local = idx - 1280; }
  else                 { src = W2   + (size_t)l * 2048 * 512; dst += 2359296; K = 2048; N = 512;  local = idx - 2304; }
  const int ntiles = N / 32;
  const int n0 = (local % ntiles) * 32, k0 = (local / ntiles) * 32;
#pragma unroll
  for (int p = 0; p < 4; ++p) {
    int row = (tid >> 5) + 8 * p, col = tid & 31;
    tl[row][col] = src[(size_t)(k0 + row) * N + n0 + col];  // tl[k][n]
  }
  __syncthreads();
  if (isFT) {
    if (tid < 128) {
      int b = tid >> 6, l2 = tid & 63;
      int nn = b * 16 + (l2 & 15);
      int kq = (l2 >> 4) * 8;
      ushort_t t8[8];
#pragma unroll
      for (int e = 0; e < 8; ++e) t8[e] = f2bf(tl[kq + e][nn]);
      size_t ad = (((size_t)((n0 >> 4) + b) * (K >> 5) + (k0 >> 5)) << 9) +
                  ((size_t)l2 << 3);
      *(uint4*)&dst[ad] = *(uint4*)t8;
    }
  } else {
#pragma unroll
    for (int p = 0; p < 4; ++p) {
      int n = (tid >> 5) + 8 * p, k = tid & 31;
      dst[(size_t)(n0 + n) * K + k0 + k] = f2bf(tl[k][n]);
    }
  }
}

// -------- bf16 MFMA GEMM body, 32x64 tile, register prefetch (Wo only) ----
__device__ __forceinline__ void gemm32x64_body(const ushort_t* __restrict__ A,
                                               const ushort_t* __restrict__ Bt,
                                               const float* __restrict__ bias,
                                               float* __restrict__ C,
                                               ushort_t* __restrict__ Cb,
                                               int N, int K, int flags,
                                               int m0, int n0) {
  __shared__ short As[32][72];
  __shared__ short Bs[64][72];
  const int tid = threadIdx.x;
  const int lane = tid & 63, wv = tid >> 6;
  const int wm = (wv >> 1) * 16, wn = (wv & 1) * 32;
  const int lm = lane & 15, quad = lane >> 4;
  const int sr = tid >> 3, sc8 = (tid & 7) * 8;

  f32x4 acc[2];
  acc[0] = (f32x4)(0.f); acc[1] = (f32x4)(0.f);

  auto loadA = [&](int k0) -> uint4 {
    return *(const uint4*)&A[(size_t)(m0 + sr) * K + k0 + sc8];
  };
  auto loadB = [&](int row, int k0) -> uint4 {
    return *(const uint4*)&Bt[(size_t)(n0 + row) * K + k0 + sc8];
  };

  uint4 aC = loadA(0), b0C = loadB(sr, 0), b1C = loadB(sr + 32, 0);

  for (int k0 = 0; k0 < K; k0 += 64) {
    const int kn = (k0 + 64 < K) ? k0 + 64 : k0;  // clamped tail reload
    uint4 aN = loadA(kn), b0N = loadB(sr, kn), b1N = loadB(sr + 32, kn);
    barrier_lds();  // prev ds_reads done; vm prefetches stay in flight
    *(uint4*)&As[sr][sc8] = aC;
    *(uint4*)&Bs[sr][sc8] = b0C;
    *(uint4*)&Bs[sr + 32][sc8] = b1C;
    barrier_lds();
#pragma unroll
    for (int kk = 0; kk < 64; kk += 32) {
      bf16x8 a = *(const bf16x8*)&As[wm + lm][kk + quad * 8];
      bf16x8 b0 = *(const bf16x8*)&Bs[wn + lm][kk + quad * 8];
      bf16x8 b1 = *(const bf16x8*)&Bs[wn + 16 + lm][kk + quad * 8];
      acc[0] = __builtin_amdgcn_mfma_f32_16x16x32_bf16(a, b0, acc[0], 0, 0, 0);
      acc[1] = __builtin_amdgcn_mfma_f32_16x16x32_bf16(a, b1, acc[1], 0, 0, 0);
    }
    aC = aN; b0C = b0N; b1C = b1N;
  }
#pragma unroll
  for (int nt = 0; nt < 2; ++nt) {
    int col = n0 + wn + nt * 16 + lm;
    float bv = (flags & 1) ? bias[col] : 0.f;
#pragma unroll
    for (int t = 0; t < 4; ++t) {
      int row = m0 + wm + quad * 4 + t;
      float v = acc[nt][t] + bv;
      if (flags & 2) v = fmaxf(v, 0.f);
      if (flags & 4) Cb[(size_t)row * N + col] = f2bf(v);
      else C[(size_t)row * N + col] = v;
    }
  }
}

__global__ __launch_bounds__(256) void k_gemm_mfma(const ushort_t* __restrict__ A,
                                                   const ushort_t* __restrict__ Bt,
                                                   const float* __restrict__ bias,
                                                   float* __restrict__ C,
                                                   ushort_t* __restrict__ Cb,
                                                   int N, int K, int flags) {
  gemm32x64_body(A, Bt, bias, C, Cb, N, K, flags, blockIdx.y * 32, blockIdx.x * 64);
}

// -------- FT GEMM: 64x128 tile, 4 waves x (32x64), global_load_lds staging,
// conflict-free fragment ds_reads, double-buffered (2 x 24KB LDS).
// flags: 1=+bias, 2=relu. omode: 0=fp32 rm, 1=bf16 rm, 2=FT(cftKT),
// 3=q(qwft=v+rwb FT, qrb=v+rrb rm), 4=k(kft FT, col-512), 5=v(vtft V^T FT).
__device__ __forceinline__ void gemm_ft_body(
    ushort_t* smem, const ushort_t* __restrict__ A, const ushort_t* __restrict__ Bt,
    const float* __restrict__ bias, int N, int K, int kBeg, int kEnd,
    int m0, int n0, int flags, int omode,
    float* __restrict__ Cf, ushort_t* __restrict__ Cb, int cftKT,
    ushort_t* __restrict__ aux, const float* __restrict__ rwb,
    const float* __restrict__ rrb) {
  const int tid = threadIdx.x;
  const int lane = tid & 63, wv = tid >> 6;
  const int wm = (wv >> 1) * 32, wn = (wv & 1) * 64;
  const int lm = lane & 15, quad = lane >> 4;
  const int AKT = K >> 5;                 // global k-tiles per 16-row block
  const int mt0 = m0 >> 4, nt0 = n0 >> 4;
  const int kt0 = kBeg >> 5;

  f32x4 acc[2][4];
#pragma unroll
  for (int i = 0; i < 2; ++i)
#pragma unroll
    for (int j = 0; j < 4; ++j) acc[i][j] = (f32x4)(0.f);

  auto stage = [&](ushort_t* dA, int ktg) {
    ushort_t* dB = dA + 4096;
#pragma unroll
    for (int it = 0; it < 6; ++it) {
      const int c = (it << 8) + tid;
      if (it < 2) {  // A chunks: c in [0,512)
        const int blk = c >> 6, ln = c & 63;
        gload16(A + (((size_t)(mt0 + (blk >> 1)) * AKT + ktg + (blk & 1)) << 9) + (ln << 3),
                dA + (c << 3));
      } else {       // B chunks: cB in [0,1024)
        const int cB = c - 512;
        const int blk = cB >> 6, ln = cB & 63;
        gload16(Bt + (((size_t)(nt0 + (blk >> 1)) * AKT + ktg + (blk & 1)) << 9) + (ln << 3),
                dB + (cB << 3));
      }
    }
  };
  auto compute = [&](const ushort_t* dA) {
    const ushort_t* dB = dA + 4096;
#pragma unroll
    for (int kk = 0; kk < 2; ++kk) {
      bf16x8 a[2], b[4];
#pragma unroll
      for (int i = 0; i < 2; ++i)
        a[i] = *(const bf16x8*)&dA[((((wm >> 4) + i) << 1) + kk) * 512 + (lane << 3)];
#pragma unroll
      for (int j = 0; j < 4; ++j)
        b[j] = *(const bf16x8*)&dB[((((wn >> 4) + j) << 1) + kk) * 512 + (lane << 3)];
#pragma unroll
      for (int i = 0; i < 2; ++i)
#pragma unroll
        for (int j = 0; j < 4; ++j)
          acc[i][j] = __builtin_amdgcn_mfma_f32_16x16x32_bf16(a[i], b[j], acc[i][j], 0, 0, 0);
    }
  };

  const int nIter = (kEnd - kBeg) >> 6;  // always even (8) here
  stage(smem, kt0);
  __syncthreads();
  for (int t = 0; t < nIter; t += 2) {
    if (t + 1 < nIter) stage(smem + 12288, kt0 + (t + 1) * 2);
    compute(smem);
    __syncthreads();
    if (t + 2 < nIter) stage(smem, kt0 + (t + 2) * 2);
    compute(smem + 12288);
    __syncthreads();
  }

#pragma unroll
  for (int i = 0; i < 2; ++i) {
    const int rowb = m0 + wm + i * 16 + quad * 4;
#pragma unroll
    for (int j = 0; j < 4; ++j) {
      const int col = n0 + wn + j * 16 + lm;
      const float bv = (flags & 1) ? bias[col] : 0.f;
#pragma unroll
      for (int t2 = 0; t2 < 4; ++t2) {
        const int row = rowb + t2;
        float v = acc[i][j][t2] + bv;
        if (flags & 2) v = fmaxf(v, 0.f);
        if (omode == 0) {
          Cf[(size_t)row * N + col] = v;
        } else if (omode == 1) {
          Cb[(size_t)row * N + col] = f2bf(v);
        } else if (omode == 2) {
          Cb[(((size_t)(row >> 4) * cftKT + (col >> 5)) << 9) +
             (((col >> 3) & 3) << 7) + ((row & 15) << 3) + (col & 7)] = f2bf(v);
        } else if (omode == 3) {
          Cb[ft512(row, col)] = f2bf(v + rwb[col]);
          aux[(size_t)row * DM + col] = f2bf(v + rrb[col]);
        } else if (omode == 4) {
          Cb[ft512(row, col - 512)] = f2bf(v);
        } else {  // omode 5: V^T FT, r = v-dim, c = token
          const int dv = col - 1024;
          Cb[((size_t)(dv >> 4) * 65 + (row >> 5)) * 512 +
             (((row >> 3) & 3) << 7) + ((dv & 15) << 3) + (row & 7)] = f2bf(v);
        }
      }
    }
  }
}

// merged QKV + Wr GEMMs (FT); q-part -> qwft(+rwb) & qrb(+rrb); k -> kft;
// v -> vtft (V^T FT); Wr -> rbg (rm)
__global__ __launch_bounds__(256) void k_gemm_qkvwr_ft(
    const ushort_t* __restrict__ wbft, const ushort_t* __restrict__ posft,
    const ushort_t* __restrict__ qkvT, const ushort_t* __restrict__ wrT,
    ushort_t* __restrict__ qwft, ushort_t* __restrict__ kft,
    ushort_t* __restrict__ vtft, ushort_t* __restrict__ rbg,
    ushort_t* __restrict__ qrb, const float* __restrict__ rwb,
    const float* __restrict__ rrb) {
  __shared__ ushort_t smem[24576];
  int m0 = blockIdx.y * 64;
  if (m0 + 64 > TT) m0 = TT - 64;  // overlapped last tile (dup writes benign)
  const int bx = blockIdx.x;
  if (bx < 12) {
    const int om = (bx < 4) ? 3 : (bx < 8 ? 4 : 5);
    ushort_t* dst = (om == 3) ? qwft : (om == 4) ? kft : vtft;
    gemm_ft_body(smem, wbft, qkvT, nullptr, QKV_N, DM, 0, DM, m0, bx * 128,
                 0, om, nullptr, dst, 0, qrb, rwb, rrb);
  } else {
    gemm_ft_body(smem, posft, wrT, nullptr, DM, DM, 0, DM, m0, (bx - 12) * 128,
                 0, 1, nullptr, rbg, 0, nullptr, nullptr, nullptr);
  }
}

// FFN1: wbft x w1T -> ff1ft (FT, K_out = DI), bias+relu
__global__ __launch_bounds__(256) void k_ffn1_ft(const ushort_t* __restrict__ wbft,
                                                 const ushort_t* __restrict__ w1T,
                                                 const float* __restrict__ b1l,
                                                 ushort_t* __restrict__ ff1ft) {
  __shared__ ushort_t smem[24576];
  int m0 = blockIdx.y * 64;
  if (m0 + 64 > TT) m0 = TT - 64;
  gemm_ft_body(smem, wbft, w1T, b1l, DI, DM, 0, DM, m0, blockIdx.x * 128,
               1 | 2, 2, nullptr, ff1ft, DI >> 5, nullptr, nullptr, nullptr);
}

// FFN2: ff1ft x w2T -> fp32 partials (split-K=4); bias folded into split 0
__global__ __launch_bounds__(256) void k_ffn2_ft(const ushort_t* __restrict__ ff1ft,
                                                 const ushort_t* __restrict__ w2T,
                                                 const float* __restrict__ b2l,
                                                 float* __restrict__ ff2p) {
  __shared__ ushort_t smem[24576];
  int m0 = blockIdx.y * 64;
  if (m0 + 64 > TT) m0 = TT - 64;
  const int s = blockIdx.z;
  gemm_ft_body(smem, ff1ft, w2T, b2l, DM, DI, s * 512, s * 512 + 512, m0,
               blockIdx.x * 128, (s == 0) ? 1 : 0, 0,
               ff2p + (size_t)s * TT * DM, nullptr, 0, nullptr, nullptr, nullptr);
}

// ---- QR GEMM: QR[h][i][k] = qr_i . r_k, written as packed causal triangle -
__global__ __launch_bounds__(256) void k_qr(const ushort_t* __restrict__ qrb,
                                            const ushort_t* __restrict__ rbg,
                                            ushort_t* __restrict__ qrp) {
  const int h = blockIdx.z;
  const int m0 = blockIdx.y * 32, n0 = blockIdx.x * 64;
  if (!(n0 == 0 || n0 + 63 >= TT - 32 - m0)) return;
  __shared__ short As[32][72];
  __shared__ short Bs[64][72];
  const int tid = threadIdx.x;
  const int lane = tid & 63, wv = tid >> 6;
  const int wm = (wv >> 1) * 16, wn = (wv & 1) * 32;
  const int lm = lane & 15, quad = lane >> 4;
  const int sr = tid >> 3, sc8 = (tid & 7) * 8;
  const uint4 zero4 = make_uint4(0, 0, 0, 0);

  *(uint4*)&As[sr][sc8] = *(const uint4*)&qrb[(size_t)(m0 + sr) * DM + h * DH + sc8];
  int br0 = n0 + sr, br1 = n0 + sr + 32;
  *(uint4*)&Bs[sr][sc8] =
      (br0 < TT) ? *(const uint4*)&rbg[(size_t)br0 * DM + h * DH + sc8] : zero4;
  *(uint4*)&Bs[sr + 32][sc8] =
      (br1 < TT) ? *(const uint4*)&rbg[(size_t)br1 * DM + h * DH + sc8] : zero4;
  __syncthreads();

  f32x4 acc[2];
  acc[0] = (f32x4)(0.f); acc[1] = (f32x4)(0.f);
#pragma unroll
  for (int kk = 0; kk < 64; kk += 32) {
    bf16x8 a = *(const bf16x8*)&As[wm + lm][kk + quad * 8];
    bf16x8 b0 = *(const bf16x8*)&Bs[wn + lm][kk + quad * 8];
    bf16x8 b1 = *(const bf16x8*)&Bs[wn + 16 + lm][kk + quad * 8];
    acc[0] = __builtin_amdgcn_mfma_f32_16x16x32_bf16(a, b0, acc[0], 0, 0, 0);
    acc[1] = __builtin_amdgcn_mfma_f32_16x16x32_bf16(a, b1, acc[1], 0, 0, 0);
  }
  const size_t hb = (size_t)h * QRP_HEAD;
#pragma unroll
  for (int nt = 0; nt < 2; ++nt) {
    int col = n0 + wn + nt * 16 + lm;
    if (col >= TT) continue;
#pragma unroll
    for (int t = 0; t < 4; ++t) {
      int row = m0 + wm + quad * 4 + t;
      float v = acc[nt][t];
      int p = row + col - (TT - 1);  // packed causal index (== j)
      size_t rb = hb + qr_rowbase(row);
      if (p >= 0) qrp[rb + p] = f2bf(v);
      if (col < 16) qrp[rb + row + 1 + col] = f2bf(v);  // wrap slot
    }
  }
}

// ------- MFMA flash attention, KVBLK=32, split-j, FT-staged Q/K/V^T -------
// Round-4 structure (27KB LDS, 5 blocks/CU) + block-uniform fast-path phase C
// for all-causal tiles + loop-invariant Q fragments in registers.
__global__ __launch_bounds__(256) void k_attn(const ushort_t* __restrict__ qwft,
                                              const ushort_t* __restrict__ kft,
                                              const ushort_t* __restrict__ vtft,
                                              const ushort_t* __restrict__ qrp,
                                              float* __restrict__ mlP,
                                              ushort_t* __restrict__ opP) {
  const int h = blockIdx.y;
  const int qt = 64 - blockIdx.x;  // heavy q-tiles dispatch first
  const int c = blockIdx.z;
  if (c > qt) return;  // empty chunk
  const int i0 = qt * 32;
  const int tid = threadIdx.x;
  const int lane = tid & 63, wv = tid >> 6;
  const int lm = lane & 15, quad = lane >> 4;

  __shared__ ushort_t qwl[2048];     // (q+rwb) 4 FT blocks [it][kt]
  __shared__ ushort_t kl[2][2048];   // K dbuf, 4 FT blocks [jt][kt]
  __shared__ ushort_t vtl[2][2048];  // V^T dbuf, 4 FT blocks [dt]
  __shared__ ushort_t pbl[1024];     // P bf16, 2 FT blocks [it]
  __shared__ float st[32][34];       // AC fp32 [i][j] (+2 pad: 2-way max)
  __shared__ float m_s[32], l_s[32], alpha_s[32];

  const int ii = tid >> 3, g = tid & 7, jjb = g * 4;
  const int i = i0 + ii;
  const size_t hb = (size_t)h * QRP_HEAD;
  const size_t qrRow = hb + qr_rowbase(i);               // this thread's QR row
  const size_t qrRowW = hb + qr_rowbase(i + 1) + i + 2;  // wrap base (i+1 row)

  const int sblk = tid >> 6, sln = tid & 63;
  auto stageKV = [&](int j0, int buf) {
    gload16(kft + (((size_t)((j0 >> 4) + (sblk >> 1)) * 16) + h * 2 + (sblk & 1)) * 512 +
                (sln << 3),
            kl[buf] + (tid << 3));
    gload16(vtft + (((size_t)(h * 4 + sblk)) * 65 + (j0 >> 5)) * 512 + (sln << 3),
            vtl[buf] + (tid << 3));
  };

  // prologue: Q tile + first K/V tile, all direct-to-LDS
  gload16(qwft + (((size_t)((i0 >> 4) + (sblk >> 1)) * 16) + h * 2 + (sblk & 1)) * 512 +
              (sln << 3),
          qwl + (tid << 3));
  stageKV(c * 32, 0);
  if (tid < 32) { m_s[tid] = -INFINITY; l_s[tid] = 0.f; }
  barrier_all();

  // Q fragments are loop-invariant: hoist to registers
  const int acit = wv >> 1, acjt = wv & 1;
  bf16x8 aQ[2];
#pragma unroll
  for (int kt = 0; kt < 2; ++kt)
    aQ[kt] = *(const bf16x8*)&qwl[(acit * 2 + kt) * 512 + (lane << 3)];

  f32x4 oA = (f32x4)(0.f);  // O^T accum, d-tile=wv, i = i0+lm
  f32x4 oB = (f32x4)(0.f);  // i = i0+16+lm

  int cur = 0;
  for (int jt = c; jt <= qt; jt += SPLIT) {
    const int j0 = jt * 32;
    // current iteration's BD values (packed causal: index == j), 4 bf16
    uint2 qr2 = *(const uint2*)&qrp[qrRow + j0 + jjb];
    // prefetch next K/V tile into the other buffer (latency hides under B-D)
    if (jt + SPLIT <= qt) stageKV((jt + SPLIT) * 32, cur ^ 1);

    {  // ---- phase B: AC MFMAs -> st ----
      f32x4 ac = (f32x4)(0.f);
#pragma unroll
      for (int kt = 0; kt < 2; ++kt) {
        bf16x8 b = *(const bf16x8*)&kl[cur][(acjt * 2 + kt) * 512 + (lane << 3)];
        ac = __builtin_amdgcn_mfma_f32_16x16x32_bf16(aQ[kt], b, ac, 0, 0, 0);
      }
#pragma unroll
      for (int t = 0; t < 4; ++t)
        st[acit * 16 + quad * 4 + t][acjt * 16 + lm] = ac[t];
    }
    barrier_lds();

    {  // ---- phase C: score assembly + online softmax ----
      float bd4[4];
      bd4[0] = bf2f((ushort_t)(qr2.x & 0xffffu));
      bd4[1] = bf2f((ushort_t)(qr2.x >> 16));
      bd4[2] = bf2f((ushort_t)(qr2.y & 0xffffu));
      bd4[3] = bf2f((ushort_t)(qr2.y >> 16));
      float sreg[4];
      if (jt < qt) {  // fast path: all-causal tile (j0+31 < i0 <= i)
#pragma unroll
        for (int u = 0; u < 4; ++u)
          sreg[u] = (st[ii][jjb + u] + bd4[u]) * ATT_SCALE;
      } else {  // diagonal tile: mask + mem-corner + wrap handling
#pragma unroll
        for (int u = 0; u < 4; ++u) {
          int j = j0 + jjb + u;
          float acv = st[ii][jjb + u];
          float s;
          if (j <= i) {
            s = (acv + bd4[u]) * ATT_SCALE;
          } else {
            bool inmem = (i < NMTOK && j < NMTOK) ||
                         (i >= TT - NMTOK && j >= TT - NMTOK);
            if (!inmem) s = -1e30f;
            else if (j == i + 1) s = acv * ATT_SCALE;  // rel_shift zero-pad
            else s = (acv + bf2f(qrp[qrRowW + (j - i - 2)])) * ATT_SCALE;  // wrap
          }
          sreg[u] = s;
        }
      }
      float tmax = fmaxf(fmaxf(sreg[0], sreg[1]), fmaxf(sreg[2], sreg[3]));
#pragma unroll
      for (int off = 1; off < 8; off <<= 1) tmax = fmaxf(tmax, __shfl_xor(tmax, off));
      const float mold = m_s[ii];
      const float mnew = fmaxf(mold, tmax);
      const float alpha = __expf(mold - mnew);
      float p[4], psum = 0.f;
#pragma unroll
      for (int u = 0; u < 4; ++u) { p[u] = __expf(sreg[u] - mnew); psum += p[u]; }
#pragma unroll
      for (int off = 1; off < 8; off <<= 1) psum += __shfl_xor(psum, off);
      uint2 pk;
      pk.x = pack2(f2bf(p[0]), f2bf(p[1]));
      pk.y = pack2(f2bf(p[2]), f2bf(p[3]));
      // P in fragment order: block it=ii>>4, offs ((g>>1)*128 + (ii&15)*8 + (g&1)*4)
      *(uint2*)&pbl[(size_t)(ii >> 4) * 512 + (g >> 1) * 128 + (ii & 15) * 8 +
                    (g & 1) * 4] = pk;
      if (g == 0) {
        m_s[ii] = mnew;
        l_s[ii] = l_s[ii] * alpha + psum;
        alpha_s[ii] = alpha;
      }
    }
    barrier_lds();

    {  // ---- phase D: O^T = O^T*alpha + V^T P^T ----
      float a0 = alpha_s[lm], a1 = alpha_s[16 + lm];
      bf16x8 av = *(const bf16x8*)&vtl[cur][wv * 512 + (lane << 3)];
      bf16x8 p0 = *(const bf16x8*)&pbl[(lane << 3)];
      bf16x8 p1 = *(const bf16x8*)&pbl[512 + (lane << 3)];
#pragma unroll
      for (int t = 0; t < 4; ++t) { oA[t] *= a0; oB[t] *= a1; }
      oA = __builtin_amdgcn_mfma_f32_16x16x32_bf16(av, p0, oA, 0, 0, 0);
      oB = __builtin_amdgcn_mfma_f32_16x16x32_bf16(av, p1, oB, 0, 0, 0);
    }
    // retire prefetch + recycle buffers (all waves past phase D)
    barrier_all();
    cur ^= 1;
  }

  {  // write partials: m, l (fp32) and un-normalized O (bf16, [i][d] layout)
    const int pidx = (qt * NH + h) * SPLIT + c;
    if (tid < 32) {
      mlP[(size_t)pidx * 64 + tid] = m_s[tid];
      mlP[(size_t)pidx * 64 + 32 + tid] = l_s[tid];
    }
    ushort_t o0[4], o1[4];
#pragma unroll
    for (int t = 0; t < 4; ++t) { o0[t] = f2bf(oA[t]); o1[t] = f2bf(oB[t]); }
    size_t ob = (size_t)pidx * 2048;
    *(uint2*)&opP[ob + (size_t)lm * 64 + wv * 16 + quad * 4] = *(uint2*)o0;
    *(uint2*)&opP[ob + (size_t)(16 + lm) * 64 + wv * 16 + quad * 4] = *(uint2*)o1;
  }
}

// -------- combine <=SPLIT chunk partials -> normalized attn output --------
__global__ __launch_bounds__(256) void k_attn_combine(const float* __restrict__ mlP,
                                                      const ushort_t* __restrict__ opP,
                                                      ushort_t* __restrict__ attnb) {
  const int qt = blockIdx.x, h = blockIdx.y;
  const int nc = (qt + 1 < SPLIT) ? qt + 1 : SPLIT;
  const int tid = threadIdx.x;
  const int i = tid >> 3, d8 = (tid & 7) * 8;
  const size_t base = (size_t)(qt * NH + h) * SPLIT;
  float m[SPLIT], l[SPLIT], wgt[SPLIT];
  float M = -INFINITY;
  for (int cc = 0; cc < nc; ++cc) {
    m[cc] = mlP[(base + cc) * 64 + i];
    l[cc] = mlP[(base + cc) * 64 + 32 + i];
    M = fmaxf(M, m[cc]);
  }
  float L = 0.f;
  for (int cc = 0; cc < nc; ++cc) { wgt[cc] = __expf(m[cc] - M); L += l[cc] * wgt[cc]; }
  float acc[8] = {0, 0, 0, 0, 0, 0, 0, 0};
  for (int cc = 0; cc < nc; ++cc) {
    uint4 v = *(const uint4*)&opP[(base + cc) * 2048 + (size_t)i * 64 + d8];
    float f[8]; unpack8(v, f);
#pragma unroll
    for (int k = 0; k < 8; ++k) acc[k] += wgt[cc] * f[k];
  }
  const float inv = 1.f / L;
  ushort_t o8[8];
#pragma unroll
  for (int k = 0; k < 8; ++k) o8[k] = f2bf(acc[k] * inv);
  *(uint4*)&attnb[(size_t)(qt * 32 + i) * DM + h * DH + d8] = *(uint4*)o8;
}

// -------- w' = LayerNorm(w + sum(delta parts)) * g + b ---------------------
__global__ __launch_bounds__(256) void k_addln(const float* __restrict__ w,
                                               float* __restrict__ wout,
                                               ushort_t* __restrict__ wbft,
                                               const float* __restrict__ delta,
                                               int nparts,
                                               const float* __restrict__ gamma,
                                               const float* __restrict__ beta) {
  const int row = blockIdx.x;
  const int tid = threadIdx.x;
  __shared__ float red[4], red2[4];
  __shared__ float sm[512];
  size_t base = (size_t)row * DM;
  float x0 = w[base + tid];
  float x1 = w[base + tid + 256];
  for (int p = 0; p < nparts; ++p) {
    x0 += delta[(size_t)p * TT * DM + base + tid];
    x1 += delta[(size_t)p * TT * DM + base + tid + 256];
  }
  float s = x0 + x1;
#pragma unroll
  for (int off = 1; off < 64; off <<= 1) s += __shfl_xor(s, off);
  if ((tid & 63) == 0) red[tid >> 6] = s;
  __syncthreads();
  float mu = (red[0] + red[1] + red[2] + red[3]) * (1.f / 512.f);
  float d0 = x0 - mu, d1 = x1 - mu;
  float v = d0 * d0 + d1 * d1;
#pragma unroll
  for (int off = 1; off < 64; off <<= 1) v += __shfl_xor(v, off);
  if ((tid & 63) == 0) red2[tid >> 6] = v;
  __syncthreads();
  float var = (red2[0] + red2[1] + red2[2] + red2[3]) * (1.f / 512.f);
  float rstd = rsqrtf(var + 1e-5f);
  float o0 = d0 * rstd * gamma[tid] + beta[tid];
  float o1 = d1 * rstd * gamma[tid + 256] + beta[tid + 256];
  wout[base + tid] = o0;
  wout[base + tid + 256] = o1;
  sm[tid] = o0; sm[tid + 256] = o1;
  __syncthreads();
  if (tid < 64) {
    const int d8 = tid << 3;
    ushort_t t8[8];
#pragma unroll
    for (int e = 0; e < 8; ++e) t8[e] = f2bf(sm[d8 + e]);
    *(uint4*)&wbft[ft512(row, d8)] = *(uint4*)t8;
  }
}

extern "C" void kernel_launch(void* const* d_in, const int* in_sizes, int n_in,
                              void* d_out, int out_size, void* d_ws, size_t ws_size,
                              hipStream_t stream) {
  const float* we   = (const float*)d_in[0];
  const float* mem  = (const float*)d_in[1];
  const float* Wqkv = (const float*)d_in[2];
  const float* Wr   = (const float*)d_in[3];
  const float* Wo   = (const float*)d_in[4];
  const float* ln1s = (const float*)d_in[5];
  const float* ln1b = (const float*)d_in[6];
  const float* W1   = (const float*)d_in[7];
  const float* b1   = (const float*)d_in[8];
  const float* W2   = (const float*)d_in[9];
  const float* b2   = (const float*)d_in[10];
  const float* ln2s = (const float*)d_in[11];
  const float* ln2b = (const float*)d_in[12];
  const float* rwb  = (const float*)d_in[13];
  const float* rrb  = (const float*)d_in[14];

  // ---- workspace layout (same footprint as before) ----
  float* w     = (float*)d_ws;                        // TT*DM fp32
  float* proj  = w + (size_t)TT * DM;                 // TT*DM fp32 (Wo out)
  ushort_t* wbft  = (ushort_t*)(proj + (size_t)TT * DM);  // TT*DM bf16 (FT)
  ushort_t* posft = wbft + (size_t)TT * DM;           // TT*DM bf16 (FT)
  ushort_t* attnb = posft + (size_t)TT * DM;          // TT*DM bf16 (rm)
  ushort_t* qkvB  = attnb + (size_t)TT * DM;          // TT*1536 bf16 region
  ushort_t* qwft  = qkvB;                             // TT*DM (Q+rwb, FT)
  ushort_t* kft   = qkvB + (size_t)TT * DM;           // TT*DM (K, FT)
  ushort_t* vtft  = qkvB + (size_t)2 * TT * DM;       // DM*TT (V^T, FT)
  ushort_t* rbg   = qkvB + (size_t)TT * QKV_N;        // TT*DM bf16 (rm)
  ushort_t* WtAll = rbg + (size_t)TT * DM;            // 4 layers x WT_STRIDE shorts
  ushort_t* opP   = WtAll + (size_t)NLAYER * WT_STRIDE;  // 65*8*SPLIT*2048 shorts
  float* mlP   = (float*)(opP + (size_t)65 * 8 * SPLIT * 2048);  // 65*8*SPLIT*64 f32
  ushort_t* qrb  = (ushort_t*)(mlP + (size_t)65 * 8 * SPLIT * 64);  // TT*DM bf16
  ushort_t* qrp  = qrb + (size_t)TT * DM;             // NH * QRP_HEAD shorts
  // overlays (time-shared, stream-ordered):
  ushort_t* ff1ft = qkvB;            // FT TT*DI bf16 spans qkv region + rbg
  float* ff2p  = (float*)opP;        // 4 split-K partials, 4*TT*DM f32 == |opP|
  const size_t OFF_QKVT = 0, OFF_WRT = 786432, OFF_WOT = 1048576,
               OFF_W1T = 1310720, OFF_W2T = 2359296;

  // all-layer weight transpose(+FT pack) + build in one dispatch
  k_prep<<<13312 + 4160, 256, 0, stream>>>(Wqkv, Wr, Wo, W1, W2, WtAll,
                                           we, mem, w, wbft, posft);

  dim3 gQW(16, 33);          // merged QKV (12 n-tiles) + Wr (4 n-tiles), 64x128
  dim3 gW1(16, 33);          // FFN1 64x128
  dim3 gW2(4, 33, 4);        // FFN2 64x128, split-K=4
  dim3 gDM32(DM / 64, 65);   // Wo (old 32x64 kernel)
  dim3 gQR(33, 65, NH);
  dim3 gA(65, NH, SPLIT);
  dim3 gC(65, NH);

  for (int l = 0; l < NLAYER; ++l) {
    const ushort_t* Wt = WtAll + (size_t)l * WT_STRIDE;
    k_gemm_qkvwr_ft<<<gQW, 256, 0, stream>>>(wbft, posft, Wt + OFF_QKVT,
                                             Wt + OFF_WRT, qwft, kft, vtft,
                                             rbg, qrb, rwb, rrb);
    k_qr<<<gQR, 256, 0, stream>>>(qrb, rbg, qrp);
    k_attn<<<gA, 256, 0, stream>>>(qwft, kft, vtft, qrp, mlP, opP);
    k_attn_combine<<<gC, 256, 0, stream>>>(mlP, opP, attnb);
    k_gemm_mfma<<<gDM32, 256, 0, stream>>>(attnb, Wt + OFF_WOT, nullptr, proj, nullptr,
                                           DM, DM, 0);
    k_addln<<<TT, 256, 0, stream>>>(w, w, wbft, proj, 1,
                                    ln1s + (size_t)l * DM, ln1b + (size_t)l * DM);
    k_ffn1_ft<<<gW1, 256, 0, stream>>>(wbft, Wt + OFF_W1T, b1 + (size_t)l * DI, ff1ft);
    k_ffn2_ft<<<gW2, 256, 0, stream>>>(ff1ft, Wt + OFF_W2T, b2 + (size_t)l * DM, ff2p);
    float* wout = (l == NLAYER - 1) ? (float*)d_out : w;
    k_addln<<<TT, 256, 0, stream>>>(w, wout, wbft, ff2p, 4,
                                    ln2s + (size_t)l * DM, ln2b + (size_t)l * DM);
  }
}